// Round 9
// baseline (482.396 us; speedup 1.0000x reference)
//
#include <hip/hip_runtime.h>
#include <hip/hip_cooperative_groups.h>
#include <math.h>

namespace cg = cooperative_groups;

#define NXI 320
#define NCI 8
#define NTI 8
#define MI  65536
#define GI  640
#define G2I (GI*GI)
#define NPIX (NXI*NXI)
#define REC_F 20          // floats per record: {du,dv,0,0, 8x(re,im)}
#define NBINS (NTI*G2I)   // 3,276,800 cells over all frames
#define SCAN_BLKS (NBINS/1024)   // 3200
#define COOP_BLKS 256
#define COOP_THR  1024
#define COOP_TOT  (COOP_BLKS*COOP_THR)   // 262144

typedef float v2f __attribute__((ext_vector_type(2)));

__device__ inline v2f cmul(v2f a, v2f b) {
    v2f axx = __builtin_shufflevector(a, a, 0, 0);
    v2f ayy = __builtin_shufflevector(a, a, 1, 1);
    v2f byx = __builtin_shufflevector(b, b, 1, 0);
    v2f r = axx * b;
    v2f t = ayy * byx;
    return r + v2f{-t.x, t.y};
}

__device__ inline v2f shfl_xor_v(v2f v, int m) {
    return v2f{__shfl_xor(v.x, m, 64), __shfl_xor(v.y, m, 64)};
}

__device__ inline int scan1024(int v, int tid, int* tmp) {
    tmp[tid] = v; __syncthreads();
    for (int d = 1; d < 1024; d <<= 1) {
        int y = (tid >= d) ? tmp[tid - d] : 0;
        __syncthreads();
        tmp[tid] += y;
        __syncthreads();
    }
    return tmp[tid];
}

// ============ ONE cooperative kernel: zero + transpose + count + scan + scatter ============
__global__ __launch_bounds__(COOP_THR, 4) void bin_coop(
    const float4* __restrict__ traj4, const float4* __restrict__ dcf4,
    const float* __restrict__ kr, const float* __restrict__ ki,
    int* __restrict__ counts, int* __restrict__ binstart,
    int* __restrict__ cursor, int* __restrict__ sums,
    float* __restrict__ trajT, float* __restrict__ dcfT,
    float* __restrict__ recs)
{
    cg::grid_group grid = cg::this_grid();
    __shared__ int tmp[COOP_THR];
    const int tid = threadIdx.x;
    const int gid = blockIdx.x * COOP_THR + tid;

    // ---- p0: zero counts ----
    {
        int4* c4 = (int4*)counts;
        for (int i = gid; i < NBINS/4; i += COOP_TOT) c4[i] = make_int4(0,0,0,0);
    }
    grid.sync();

    // ---- p1: transpose traj/dcf (coalesced) + count cells ----
    if (gid < MI) {
        int m = gid;
        float4 t0 = traj4[m*4+0], t1 = traj4[m*4+1];
        float4 t2 = traj4[m*4+2], t3 = traj4[m*4+3];
        float4 d0 = dcf4[m*2+0],  d1 = dcf4[m*2+1];
        float u[8]  = {t0.x,t0.y,t0.z,t0.w, t1.x,t1.y,t1.z,t1.w};
        float v[8]  = {t2.x,t2.y,t2.z,t2.w, t3.x,t3.y,t3.z,t3.w};
        float dd[8] = {d0.x,d0.y,d0.z,d0.w, d1.x,d1.y,d1.z,d1.w};
        #pragma unroll
        for (int f = 0; f < NTI; ++f) {
            trajT[(f*2+0)*MI + m] = u[f];
            trajT[(f*2+1)*MI + m] = v[f];
            dcfT[f*MI + m] = dd[f];
            float uu = (u[f] + 0.5f) * (float)GI;
            float vv = (v[f] + 0.5f) * (float)GI;
            int i0 = (int)floorf(uu) + GI/2; if (i0 >= GI) i0 -= GI;
            int j0 = (int)floorf(vv) + GI/2; if (j0 >= GI) j0 -= GI;
            atomicAdd(&counts[f*G2I + i0*GI + j0], 1);
        }
    }
    grid.sync();

    // ---- p2: scanA (local exclusive per 1024-chunk + chunk totals) ----
    for (int vb = blockIdx.x; vb < SCAN_BLKS; vb += COOP_BLKS) {
        __syncthreads();
        int i = vb*1024 + tid;
        int v = counts[i];
        int incl = scan1024(v, tid, tmp);
        binstart[i] = incl - v;
        if (tid == 1023) sums[vb] = incl;
    }
    grid.sync();

    // ---- p3: scanB over 3200 chunk sums (block 0) ----
    if (blockIdx.x == 0) {
        int base = tid * 4;
        int v[4]; int s = 0;
        #pragma unroll
        for (int q = 0; q < 4; ++q) {
            int idx = base + q;
            v[q] = (idx < SCAN_BLKS) ? sums[idx] : 0;
            s += v[q];
        }
        int incl = scan1024(s, tid, tmp);
        int run = incl - s;
        #pragma unroll
        for (int q = 0; q < 4; ++q) {
            int idx = base + q;
            if (idx < SCAN_BLKS) sums[idx] = run;
            run += v[q];
        }
    }
    grid.sync();

    // ---- p4: apply chunk offsets; init cursor; sentinel ----
    for (int i = gid; i < NBINS; i += COOP_TOT) {
        int v = binstart[i] + sums[i >> 10];
        binstart[i] = v;
        cursor[i] = v;
    }
    if (gid == 0) binstart[NBINS] = NTI * MI;
    grid.sync();

    // ---- p5: scatter records into bin-sorted slots ----
    for (int g2 = gid; g2 < NTI*MI; g2 += COOP_TOT) {
        int f = g2 >> 16, m = g2 & (MI - 1);
        float tu = trajT[(f*2+0)*MI + m];
        float tv = trajT[(f*2+1)*MI + m];
        float w  = dcfT[f*MI + m];
        float uu = (tu + 0.5f) * (float)GI;
        float vv = (tv + 0.5f) * (float)GI;
        float fu = floorf(uu), fv = floorf(vv);
        float du = uu - fu, dv = vv - fv;
        int i0s = (int)fu + GI/2; if (i0s >= GI) i0s -= GI;
        int j0s = (int)fv + GI/2; if (j0s >= GI) j0s -= GI;
        int slot = atomicAdd(&cursor[f*G2I + i0s*GI + j0s], 1);
        float4* r = (float4*)(recs + (size_t)slot * REC_F);
        r[0] = make_float4(du, dv, 0.f, 0.f);
        #pragma unroll
        for (int q = 0; q < 4; ++q) {
            int c0 = 2*q;
            r[1+q] = make_float4(kr[c0*MI + m]*w,     ki[c0*MI + m]*w,
                                 kr[(c0+1)*MI + m]*w, ki[(c0+1)*MI + m]*w);
        }
    }
}

// ---------------- register-resident 640-pt iFFT (sign +), packed ----------------
__device__ inline void dft5p(v2f x0, v2f x1, v2f x2, v2f x3, v2f x4, v2f* X)
{
    const float c1 = 0.309016994f, c2 = -0.809016994f;
    const float s1 = 0.951056516f, s2 =  0.587785252f;
    v2f S1 = x1 + x4, D1 = x1 - x4;
    v2f S2 = x2 + x3, D2 = x2 - x3;
    X[0] = x0 + S1 + S2;
    v2f A = x0 + c1*S1 + c2*S2;
    v2f T = s1*D1 + s2*D2;
    v2f B = x0 + c2*S1 + c1*S2;
    v2f U = s2*D1 - s1*D2;
    v2f iT = v2f{-T.y, T.x};
    v2f iU = v2f{-U.y, U.x};
    X[1] = A + iT;  X[4] = A - iT;
    X[2] = B + iU;  X[3] = B - iU;
}

__device__ inline void fft640_pruned(v2f* a, int lane, v2f* line, int xorm)
{
    const float PI = 3.14159265358979f;
    #pragma unroll
    for (int s = 0; s < 6; ++s) {
        const int h = 32 >> s;
        bool low = (lane & h) == 0;
        int k = (lane << s) & 63;
        float sn, cs;
        __sincosf((2.0f * PI / 64.0f) * (float)k, &sn, &cs);
        v2f ws = v2f{cs, sn};
        #pragma unroll
        for (int n = 0; n < 10; ++n) {
            v2f p = shfl_xor_v(a[n], h);
            v2f tl = p + a[n];
            v2f th = cmul(a[n] - p, ws);
            a[n] = low ? tl : th;
        }
    }
    int k1 = __brev(lane) >> 26;
    float th2 = (2.0f * PI / 640.0f) * (float)k1;
    float sn, cs;
    __sincosf(th2, &sn, &cs);
    v2f wb = v2f{cs, sn};
    v2f w = wb;
    #pragma unroll
    for (int n = 1; n < 10; ++n) {
        a[n] = cmul(a[n], w);
        w = cmul(w, wb);
    }
    v2f E[5], O[5];
    dft5p(a[0], a[2], a[4], a[6], a[8], E);
    dft5p(a[1], a[3], a[5], a[7], a[9], O);
    const v2f tk1 = { 0.809016994f, 0.587785252f};
    const v2f tk2 = { 0.309016994f, 0.951056516f};
    const v2f tk3 = {-0.309016994f, 0.951056516f};
    const v2f tk4 = {-0.809016994f, 0.587785252f};
    v2f t1 = cmul(tk1, O[1]);
    v2f t2 = cmul(tk2, O[2]);
    v2f t3 = cmul(tk3, O[3]);
    v2f t4 = cmul(tk4, O[4]);
    bool hi = (k1 >= 32);
    line[(160 + k1) ^ xorm] = E[0] + O[0];          // k2=0
    line[(224 + k1) ^ xorm] = E[1] + t1;            // k2=1
    int yx = hi ? (k1 - 32) : (288 + k1);           // k2=7 : k2=2
    v2f zx = hi ? (E[2] - t2) : (E[2] + t2);
    line[yx ^ xorm] = zx;
    line[(32 + k1) ^ xorm] = E[3] - t3;             // k2=8
    line[(96 + k1) ^ xorm] = E[4] - t4;             // k2=9
}

// ---- fused atomic-free gather + row FFT: block = (frame, grid-row i) ----
__global__ __launch_bounds__(512, 8) void row_fft(
    const int* __restrict__ binstart, const float* __restrict__ recs,
    v2f* __restrict__ rowout)
{
    __shared__ v2f A[NCI][GI];      // 40,960 B exactly -> 4 blocks/CU
    int bid = blockIdx.x;           // f*GI + i
    int i = bid % GI;
    int f = bid / GI;
    int tid = threadIdx.x;
    int im1 = i ? i - 1 : GI - 1;
    const int* bsr[2] = { binstart + f*G2I + i*GI,
                          binstart + f*G2I + im1*GI };

    for (int j = tid; j < GI; j += 512) {
        v2f acc[NCI];
        #pragma unroll
        for (int c = 0; c < NCI; ++c) acc[c] = v2f{0.f, 0.f};
        #pragma unroll
        for (int p = 0; p < 2; ++p) {
            const int* bs = bsr[p];
            if (j > 0) {
                int lo = bs[j-1], mid = bs[j], hi = bs[j+1];
                for (int s = lo; s < hi; ++s) {
                    const float4* R = (const float4*)(recs + (size_t)s*REC_F);
                    float4 h4 = R[0];
                    float wr = p ? h4.x : (1.f - h4.x);
                    float w  = wr * ((s < mid) ? h4.y : (1.f - h4.y));
                    float4 d0 = R[1], d1 = R[2], d2 = R[3], d3 = R[4];
                    acc[0] += w * v2f{d0.x, d0.y};  acc[1] += w * v2f{d0.z, d0.w};
                    acc[2] += w * v2f{d1.x, d1.y};  acc[3] += w * v2f{d1.z, d1.w};
                    acc[4] += w * v2f{d2.x, d2.y};  acc[5] += w * v2f{d2.z, d2.w};
                    acc[6] += w * v2f{d3.x, d3.y};  acc[7] += w * v2f{d3.z, d3.w};
                }
            } else {
                #pragma unroll
                for (int side = 0; side < 2; ++side) {
                    int b = side ? 0 : (GI - 1);
                    int s0 = bs[b], s1 = bs[b+1];
                    for (int s = s0; s < s1; ++s) {
                        const float4* R = (const float4*)(recs + (size_t)s*REC_F);
                        float4 h4 = R[0];
                        float wr = p ? h4.x : (1.f - h4.x);
                        float w  = wr * (side ? (1.f - h4.y) : h4.y);
                        float4 d0 = R[1], d1 = R[2], d2 = R[3], d3 = R[4];
                        acc[0] += w * v2f{d0.x, d0.y};  acc[1] += w * v2f{d0.z, d0.w};
                        acc[2] += w * v2f{d1.x, d1.y};  acc[3] += w * v2f{d1.z, d1.w};
                        acc[4] += w * v2f{d2.x, d2.y};  acc[5] += w * v2f{d2.z, d2.w};
                        acc[6] += w * v2f{d3.x, d3.y};  acc[7] += w * v2f{d3.z, d3.w};
                    }
                }
            }
        }
        #pragma unroll
        for (int c = 0; c < NCI; ++c) A[c][j] = acc[c];
    }
    __syncthreads();

    int wv = tid >> 6, lane = tid & 63;
    v2f a[10];
    #pragma unroll
    for (int n = 0; n < 10; ++n) a[n] = A[wv][10*lane + n];
    fft640_pruned(a, lane, A[wv], 0);
    v2f* dst = rowout + (((size_t)f*NCI + wv)*GI + i)*NXI;
    #pragma unroll
    for (int q = 0; q < 5; ++q) {
        int yc = lane + 64*q;
        dst[yc] = A[wv][yc];
    }
}

// ---- col FFT + crop: block = (frame, coil, y-group of 8) ----
__global__ __launch_bounds__(512, 8) void col_fft(
    const v2f* __restrict__ rowout, v2f* __restrict__ colimg)
{
    __shared__ v2f A[8][GI];
    int bid = blockIdx.x;
    int g = bid % 40;
    int c = (bid / 40) % NCI;
    int f = bid / (40*NCI);
    int y0 = g * 8;
    int tid = threadIdx.x;
    const v2f* src = rowout + ((size_t)f*NCI + c)*GI*NXI + y0;
    for (int idx = tid; idx < 8*GI; idx += 512) {
        int l = idx & 7, k = idx >> 3;
        A[l][k ^ (4*(l & 3))] = src[(size_t)k*NXI + l];
    }
    __syncthreads();
    int wv = tid >> 6, lane = tid & 63;
    int xm = 4 * (wv & 3);
    v2f a[10];
    #pragma unroll
    for (int n = 0; n < 10; ++n) a[n] = A[wv][(10*lane + n) ^ xm];
    fft640_pruned(a, lane, A[wv], xm);
    __syncthreads();
    v2f* dst = colimg + ((size_t)f*NCI + c)*NPIX + y0;
    for (int idx = tid; idx < 8*NXI; idx += 512) {
        int l = idx & 7, xx = idx >> 3;
        dst[(size_t)xx*NXI + l] = A[l][xx ^ (4*(l & 3))];
    }
}

// ------------- deapodize + coil combine -------------
__global__ __launch_bounds__(256) void combine_kernel(
    const float2* __restrict__ colimg, const float* __restrict__ csr,
    const float* __restrict__ csi, float2* __restrict__ img)
{
    int f = blockIdx.y;
    int pix = blockIdx.x * 256 + threadIdx.x;
    int x = pix / NXI, y = pix - x*NXI;
    const float PI = 3.14159265358979f;
    float tx = (x - 160) * (1.0f/GI);
    float ty = (y - 160) * (1.0f/GI);
    float dx = 1.0f, dy = 1.0f;
    if (x != 160) { float s = __sinf(PI*tx) / (PI*tx); dx = s*s; }
    if (y != 160) { float s = __sinf(PI*ty) / (PI*ty); dy = s*s; }
    float scale = 1.0f / ((float)G2I * dx * dy);
    float accr = 0.f, acci = 0.f;
    #pragma unroll
    for (int c = 0; c < NCI; ++c) {
        float2 g = colimg[((size_t)f*NCI + c)*NPIX + pix];
        float cr = csr[c*NPIX + pix];
        float ci = csi[c*NPIX + pix];
        accr += cr*g.x + ci*g.y;
        acci += cr*g.y - ci*g.x;
    }
    img[(size_t)f*NPIX + pix] = make_float2(accr*scale, acci*scale);
}

// ---------------- warp all frames + sum ----------------
__global__ __launch_bounds__(256) void warp_sum(
    const float2* __restrict__ img, const float* __restrict__ motions,
    float* __restrict__ out)
{
    int pix = blockIdx.x * 256 + threadIdx.x;
    int x = pix / NXI, y = pix - x*NXI;
    float accr = 0.f, acci = 0.f;
    #pragma unroll
    for (int f = 0; f < NTI; ++f) {
        float fx = motions[(size_t)(pix*2 + 0)*NTI + f];
        float fy = motions[(size_t)(pix*2 + 1)*NTI + f];
        float xs = fminf(fmaxf((float)x + fx, 0.0f), (float)(NXI-1));
        float ys = fminf(fmaxf((float)y + fy, 0.0f), (float)(NXI-1));
        int x0 = (int)floorf(xs);
        int y0 = (int)floorf(ys);
        int x1 = min(x0+1, NXI-1);
        int y1 = min(y0+1, NXI-1);
        float dx = xs - (float)x0;
        float dy = ys - (float)y0;
        const float2* im = img + (size_t)f*NPIX;
        float2 v00 = im[x0*NXI + y0];
        float2 v10 = im[x1*NXI + y0];
        float2 v01 = im[x0*NXI + y1];
        float2 v11 = im[x1*NXI + y1];
        float w00 = (1.f-dx)*(1.f-dy), w10 = dx*(1.f-dy);
        float w01 = (1.f-dx)*dy,       w11 = dx*dy;
        accr += w00*v00.x + w10*v10.x + w01*v01.x + w11*v11.x;
        acci += w00*v00.y + w10*v10.y + w01*v01.y + w11*v11.y;
    }
    out[pix*2+0] = accr;
    out[pix*2+1] = acci;
}

extern "C" void kernel_launch(void* const* d_in, const int* in_sizes, int n_in,
                              void* d_out, int out_size, void* d_ws, size_t ws_size,
                              hipStream_t stream)
{
    const float* kr   = (const float*)d_in[0];
    const float* ki   = (const float*)d_in[1];
    const float* traj = (const float*)d_in[2];
    const float* csr  = (const float*)d_in[3];
    const float* csi  = (const float*)d_in[4];
    const float* dcf  = (const float*)d_in[5];
    const float* mot  = (const float*)d_in[6];
    float* out = (float*)d_out;

    char* ws = (char*)d_ws;
    float*  recs     = (float*)ws;                       // 41.94 MB
    ws += (size_t)NTI * MI * REC_F * sizeof(float);
    v2f*    rowout   = (v2f*)ws;                         // 104.86 MB
    ws += (size_t)NTI * NCI * GI * NXI * sizeof(float2);
    float2* colimg   = (float2*)ws;                      // 52.43 MB
    ws += (size_t)NTI * NCI * NPIX * sizeof(float2);
    float2* img      = (float2*)ws;                      // 6.55 MB
    ws += (size_t)NTI * NPIX * sizeof(float2);
    int*    counts   = (int*)ws;  ws += (size_t)NBINS * sizeof(int);        // 13.1 MB
    int*    binstart = (int*)ws;  ws += ((size_t)NBINS + 16) * sizeof(int); // 13.1 MB
    int*    cursor   = (int*)ws;  ws += (size_t)NBINS * sizeof(int);        // 13.1 MB
    int*    sums     = (int*)ws;  ws += 16384;
    float*  trajT    = (float*)ws; ws += (size_t)NTI * 2 * MI * sizeof(float); // 4.19 MB
    float*  dcfT     = (float*)ws; ws += (size_t)NTI * MI * sizeof(float);     // 2.10 MB

    const float4* traj4 = (const float4*)traj;
    const float4* dcf4  = (const float4*)dcf;

    void* kargs[] = {
        (void*)&traj4, (void*)&dcf4, (void*)&kr, (void*)&ki,
        (void*)&counts, (void*)&binstart, (void*)&cursor, (void*)&sums,
        (void*)&trajT, (void*)&dcfT, (void*)&recs
    };
    hipLaunchCooperativeKernel((void*)bin_coop, dim3(COOP_BLKS), dim3(COOP_THR),
                               kargs, 0, stream);

    row_fft      <<<NTI*GI,     512, 0, stream>>>(binstart, recs, rowout);
    col_fft      <<<NTI*NCI*40, 512, 0, stream>>>(rowout, (v2f*)colimg);
    combine_kernel<<<dim3(NPIX/256, NTI), 256, 0, stream>>>(colimg, csr, csi, img);
    warp_sum     <<<NPIX/256,   256, 0, stream>>>(img, mot, out);
}

// Round 10
// 304.540 us; speedup vs baseline: 1.5840x; 1.5840x over previous
//
#include <hip/hip_runtime.h>
#include <math.h>

#define NXI 320
#define NCI 8
#define NTI 8
#define MI  65536
#define GI  640
#define G2I (GI*GI)
#define NPIX (NXI*NXI)
#define REC_F 20          // floats per record: {du,dv,0,0, 8x(re,im)}
#define NBINS (NTI*G2I)   // 3,276,800 cells over all frames
#define SCAN_BLKS (NBINS/1024)   // 3200

typedef float v2f __attribute__((ext_vector_type(2)));

__device__ inline v2f cmul(v2f a, v2f b) {
    v2f axx = __builtin_shufflevector(a, a, 0, 0);
    v2f ayy = __builtin_shufflevector(a, a, 1, 1);
    v2f byx = __builtin_shufflevector(b, b, 1, 0);
    v2f r = axx * b;
    v2f t = ayy * byx;
    return r + v2f{-t.x, t.y};
}

__device__ inline v2f shfl_xor_v(v2f v, int m) {
    return v2f{__shfl_xor(v.x, m, 64), __shfl_xor(v.y, m, 64)};
}

__device__ inline void cell_of(const float* __restrict__ traj, int m, int f,
                               int& i0s, int& j0s, float& du, float& dv)
{
    float tu = traj[(m*2 + 0)*NTI + f];
    float tv = traj[(m*2 + 1)*NTI + f];
    float u = (tu + 0.5f) * (float)GI;
    float v = (tv + 0.5f) * (float)GI;
    float fu = floorf(u), fv = floorf(v);
    du = u - fu; dv = v - fv;
    i0s = (int)fu + GI/2; if (i0s >= GI) i0s -= GI;   // ifftshift folded in
    j0s = (int)fv + GI/2; if (j0s >= GI) j0s -= GI;
}

// ---------------- cell-level counting sort, all frames ----------------
__global__ __launch_bounds__(256) void count_cells(
    const float* __restrict__ traj, int* __restrict__ counts)
{
    int tid = blockIdx.x * 256 + threadIdx.x;   // f*MI + m
    int f = tid >> 16, m = tid & (MI - 1);
    int i0s, j0s; float du, dv;
    cell_of(traj, m, f, i0s, j0s, du, dv);
    atomicAdd(&counts[f*G2I + i0s*GI + j0s], 1);
}

__device__ inline int scan1024(int v, int tid, int* tmp) {
    tmp[tid] = v; __syncthreads();
    for (int d = 1; d < 1024; d <<= 1) {
        int y = (tid >= d) ? tmp[tid - d] : 0;
        __syncthreads();
        tmp[tid] += y;
        __syncthreads();
    }
    return tmp[tid];
}

__global__ __launch_bounds__(1024) void scanA(const int* __restrict__ counts,
                                              int* __restrict__ binstart,
                                              int* __restrict__ sums)
{
    __shared__ int tmp[1024];
    int tid = threadIdx.x;
    int i = blockIdx.x * 1024 + tid;
    int v = counts[i];
    int incl = scan1024(v, tid, tmp);
    binstart[i] = incl - v;                   // chunk-local exclusive
    if (tid == 1023) sums[blockIdx.x] = incl;
}

// exclusive scan of the 3200 chunk sums + sentinels (one block)
__global__ __launch_bounds__(1024) void scanB(int* __restrict__ sums,
                                              int* __restrict__ binstart)
{
    __shared__ int tmp[1024];
    int tid = threadIdx.x;
    int base = tid * 4;
    int v[4]; int s = 0;
    #pragma unroll
    for (int q = 0; q < 4; ++q) {
        int idx = base + q;
        v[q] = (idx < SCAN_BLKS) ? sums[idx] : 0;
        s += v[q];
    }
    int incl = scan1024(s, tid, tmp);
    int run = incl - s;
    #pragma unroll
    for (int q = 0; q < 4; ++q) {
        int idx = base + q;
        if (idx < SCAN_BLKS) sums[idx] = run;
        run += v[q];
    }
    if (tid == SCAN_BLKS/4 - 1) {           // run == grand total here
        sums[SCAN_BLKS] = run;              // sentinel chunk offset
        binstart[NBINS] = 0;                // so gstart(NBINS) == total
    }
}

// slot via atomicSub on counts — no cursor array, no scanC
__global__ __launch_bounds__(256) void scatter_cells(
    const float* __restrict__ kr, const float* __restrict__ ki,
    const float* __restrict__ traj, const float* __restrict__ dcf,
    int* __restrict__ counts, const int* __restrict__ binstart,
    const int* __restrict__ sums, float* __restrict__ recs)
{
    int tid = blockIdx.x * 256 + threadIdx.x;   // f*MI + m
    int f = tid >> 16, m = tid & (MI - 1);
    int i0s, j0s; float du, dv;
    cell_of(traj, m, f, i0s, j0s, du, dv);
    float w = dcf[m*NTI + f];
    int bin = f*G2I + i0s*GI + j0s;
    int within = atomicSub(&counts[bin], 1) - 1;
    int slot = binstart[bin] + sums[bin >> 10] + within;
    float4* r = (float4*)(recs + (size_t)slot * REC_F);
    r[0] = make_float4(du, dv, 0.f, 0.f);
    #pragma unroll
    for (int q = 0; q < 4; ++q) {
        int c0 = 2*q;
        r[1+q] = make_float4(kr[c0*MI + m]*w,     ki[c0*MI + m]*w,
                             kr[(c0+1)*MI + m]*w, ki[(c0+1)*MI + m]*w);
    }
}

// ---------------- register-resident 640-pt iFFT (sign +), packed ----------------
__device__ inline void dft5p(v2f x0, v2f x1, v2f x2, v2f x3, v2f x4, v2f* X)
{
    const float c1 = 0.309016994f, c2 = -0.809016994f;
    const float s1 = 0.951056516f, s2 =  0.587785252f;
    v2f S1 = x1 + x4, D1 = x1 - x4;
    v2f S2 = x2 + x3, D2 = x2 - x3;
    X[0] = x0 + S1 + S2;
    v2f A = x0 + c1*S1 + c2*S2;
    v2f T = s1*D1 + s2*D2;
    v2f B = x0 + c2*S1 + c1*S2;
    v2f U = s2*D1 - s1*D2;
    v2f iT = v2f{-T.y, T.x};
    v2f iU = v2f{-U.y, U.x};
    X[1] = A + iT;  X[4] = A - iT;
    X[2] = B + iU;  X[3] = B - iU;
}

__device__ inline void fft640_pruned(v2f* a, int lane, v2f* line, int xorm)
{
    const float PI = 3.14159265358979f;
    // 6 across-lane DIF stages: t = p + sg*a (pk_fma), then cmul by
    // per-lane w hoisted out of the value loop (w=1 for low lanes).
    // High-lane twiddle exponent (lane<<s)&31 — r5-verified sign convention.
    #pragma unroll
    for (int s = 0; s < 6; ++s) {
        const int h = 32 >> s;
        bool low = (lane & h) == 0;
        int kp = (lane << s) & 31;
        float sn, cs;
        __sincosf((2.0f * PI / 64.0f) * (float)kp, &sn, &cs);
        v2f w = low ? v2f{1.f, 0.f} : v2f{cs, sn};
        float sg = low ? 1.f : -1.f;
        v2f sgv = v2f{sg, sg};
        #pragma unroll
        for (int n = 0; n < 10; ++n) {
            v2f p = shfl_xor_v(a[n], h);
            v2f t = sgv * a[n] + p;        // low: p+a ; high: p-a
            a[n] = cmul(t, w);
        }
    }
    int k1 = __brev(lane) >> 26;
    float th2 = (2.0f * PI / 640.0f) * (float)k1;
    float sn, cs;
    __sincosf(th2, &sn, &cs);
    v2f wb = v2f{cs, sn};
    v2f w = wb;
    #pragma unroll
    for (int n = 1; n < 10; ++n) {
        a[n] = cmul(a[n], w);
        w = cmul(w, wb);
    }
    v2f E[5], O[5];
    dft5p(a[0], a[2], a[4], a[6], a[8], E);
    dft5p(a[1], a[3], a[5], a[7], a[9], O);
    const v2f tk1 = { 0.809016994f, 0.587785252f};
    const v2f tk2 = { 0.309016994f, 0.951056516f};
    const v2f tk3 = {-0.309016994f, 0.951056516f};
    const v2f tk4 = {-0.809016994f, 0.587785252f};
    v2f t1 = cmul(tk1, O[1]);
    v2f t2 = cmul(tk2, O[2]);
    v2f t3 = cmul(tk3, O[3]);
    v2f t4 = cmul(tk4, O[4]);
    bool hi = (k1 >= 32);
    line[(160 + k1) ^ xorm] = E[0] + O[0];          // k2=0
    line[(224 + k1) ^ xorm] = E[1] + t1;            // k2=1
    int yx = hi ? (k1 - 32) : (288 + k1);           // k2=7 : k2=2
    v2f zx = hi ? (E[2] - t2) : (E[2] + t2);
    line[yx ^ xorm] = zx;
    line[(32 + k1) ^ xorm] = E[3] - t3;             // k2=8
    line[(96 + k1) ^ xorm] = E[4] - t4;             // k2=9
}

// ---- fused atomic-free gather + row FFT: block = (frame, grid-row i) ----
__global__ __launch_bounds__(512, 8) void row_fft(
    const int* __restrict__ binstart, const int* __restrict__ sums,
    const float* __restrict__ recs, v2f* __restrict__ rowout)
{
    __shared__ v2f A[NCI][GI];      // 40,960 B exactly -> 4 blocks/CU
    int bid = blockIdx.x;           // f*GI + i
    int i = bid % GI;
    int f = bid / GI;
    int tid = threadIdx.x;
    int im1 = i ? i - 1 : GI - 1;
    const int base0 = f*G2I + i*GI;     // p=0: row i   (1-du)
    const int base1 = f*G2I + im1*GI;   // p=1: row i-1 (du)

    #define GS(b) (binstart[b] + sums[(b) >> 10])

    for (int j = tid; j < GI; j += 512) {
        v2f acc[NCI];
        #pragma unroll
        for (int c = 0; c < NCI; ++c) acc[c] = v2f{0.f, 0.f};
        #pragma unroll
        for (int p = 0; p < 2; ++p) {
            const int base = p ? base1 : base0;
            if (j > 0) {
                int lo = GS(base + j - 1), mid = GS(base + j), hi = GS(base + j + 1);
                for (int s = lo; s < hi; ++s) {
                    const float4* R = (const float4*)(recs + (size_t)s*REC_F);
                    float4 h4 = R[0];
                    float wr = p ? h4.x : (1.f - h4.x);
                    float w  = wr * ((s < mid) ? h4.y : (1.f - h4.y));
                    float4 d0 = R[1], d1 = R[2], d2 = R[3], d3 = R[4];
                    acc[0] += w * v2f{d0.x, d0.y};  acc[1] += w * v2f{d0.z, d0.w};
                    acc[2] += w * v2f{d1.x, d1.y};  acc[3] += w * v2f{d1.z, d1.w};
                    acc[4] += w * v2f{d2.x, d2.y};  acc[5] += w * v2f{d2.z, d2.w};
                    acc[6] += w * v2f{d3.x, d3.y};  acc[7] += w * v2f{d3.z, d3.w};
                }
            } else {
                #pragma unroll
                for (int side = 0; side < 2; ++side) {
                    int b = base + (side ? 0 : (GI - 1));
                    int s0 = GS(b), s1 = GS(b + 1);
                    for (int s = s0; s < s1; ++s) {
                        const float4* R = (const float4*)(recs + (size_t)s*REC_F);
                        float4 h4 = R[0];
                        float wr = p ? h4.x : (1.f - h4.x);
                        float w  = wr * (side ? (1.f - h4.y) : h4.y);
                        float4 d0 = R[1], d1 = R[2], d2 = R[3], d3 = R[4];
                        acc[0] += w * v2f{d0.x, d0.y};  acc[1] += w * v2f{d0.z, d0.w};
                        acc[2] += w * v2f{d1.x, d1.y};  acc[3] += w * v2f{d1.z, d1.w};
                        acc[4] += w * v2f{d2.x, d2.y};  acc[5] += w * v2f{d2.z, d2.w};
                        acc[6] += w * v2f{d3.x, d3.y};  acc[7] += w * v2f{d3.z, d3.w};
                    }
                }
            }
        }
        #pragma unroll
        for (int c = 0; c < NCI; ++c) A[c][j] = acc[c];
    }
    #undef GS
    __syncthreads();

    int wv = tid >> 6, lane = tid & 63;
    v2f a[10];
    #pragma unroll
    for (int n = 0; n < 10; ++n) a[n] = A[wv][10*lane + n];
    fft640_pruned(a, lane, A[wv], 0);
    v2f* dst = rowout + (((size_t)f*NCI + wv)*GI + i)*NXI;
    #pragma unroll
    for (int q = 0; q < 5; ++q) {
        int yc = lane + 64*q;
        dst[yc] = A[wv][yc];
    }
}

// ---- col FFT + crop: block = (frame, coil, y-group of 8) ----
__global__ __launch_bounds__(512, 8) void col_fft(
    const v2f* __restrict__ rowout, v2f* __restrict__ colimg)
{
    __shared__ v2f A[8][GI];
    int bid = blockIdx.x;
    int g = bid % 40;
    int c = (bid / 40) % NCI;
    int f = bid / (40*NCI);
    int y0 = g * 8;
    int tid = threadIdx.x;
    const v2f* src = rowout + ((size_t)f*NCI + c)*GI*NXI + y0;
    for (int idx = tid; idx < 8*GI; idx += 512) {
        int l = idx & 7, k = idx >> 3;
        A[l][k ^ (4*(l & 3))] = src[(size_t)k*NXI + l];
    }
    __syncthreads();
    int wv = tid >> 6, lane = tid & 63;
    int xm = 4 * (wv & 3);
    v2f a[10];
    #pragma unroll
    for (int n = 0; n < 10; ++n) a[n] = A[wv][(10*lane + n) ^ xm];
    fft640_pruned(a, lane, A[wv], xm);
    __syncthreads();
    v2f* dst = colimg + ((size_t)f*NCI + c)*NPIX + y0;
    for (int idx = tid; idx < 8*NXI; idx += 512) {
        int l = idx & 7, xx = idx >> 3;
        dst[(size_t)xx*NXI + l] = A[l][xx ^ (4*(l & 3))];
    }
}

// ------------- deapodize + coil combine -------------
__global__ __launch_bounds__(256) void combine_kernel(
    const float2* __restrict__ colimg, const float* __restrict__ csr,
    const float* __restrict__ csi, float2* __restrict__ img)
{
    int f = blockIdx.y;
    int pix = blockIdx.x * 256 + threadIdx.x;
    int x = pix / NXI, y = pix - x*NXI;
    const float PI = 3.14159265358979f;
    float tx = (x - 160) * (1.0f/GI);
    float ty = (y - 160) * (1.0f/GI);
    float dx = 1.0f, dy = 1.0f;
    if (x != 160) { float s = __sinf(PI*tx) / (PI*tx); dx = s*s; }
    if (y != 160) { float s = __sinf(PI*ty) / (PI*ty); dy = s*s; }
    float scale = 1.0f / ((float)G2I * dx * dy);
    float accr = 0.f, acci = 0.f;
    #pragma unroll
    for (int c = 0; c < NCI; ++c) {
        float2 g = colimg[((size_t)f*NCI + c)*NPIX + pix];
        float cr = csr[c*NPIX + pix];
        float ci = csi[c*NPIX + pix];
        accr += cr*g.x + ci*g.y;
        acci += cr*g.y - ci*g.x;
    }
    img[(size_t)f*NPIX + pix] = make_float2(accr*scale, acci*scale);
}

// ---------------- warp all frames + sum ----------------
__global__ __launch_bounds__(256) void warp_sum(
    const float2* __restrict__ img, const float* __restrict__ motions,
    float* __restrict__ out)
{
    int pix = blockIdx.x * 256 + threadIdx.x;
    int x = pix / NXI, y = pix - x*NXI;
    float accr = 0.f, acci = 0.f;
    #pragma unroll
    for (int f = 0; f < NTI; ++f) {
        float fx = motions[(size_t)(pix*2 + 0)*NTI + f];
        float fy = motions[(size_t)(pix*2 + 1)*NTI + f];
        float xs = fminf(fmaxf((float)x + fx, 0.0f), (float)(NXI-1));
        float ys = fminf(fmaxf((float)y + fy, 0.0f), (float)(NXI-1));
        int x0 = (int)floorf(xs);
        int y0 = (int)floorf(ys);
        int x1 = min(x0+1, NXI-1);
        int y1 = min(y0+1, NXI-1);
        float dx = xs - (float)x0;
        float dy = ys - (float)y0;
        const float2* im = img + (size_t)f*NPIX;
        float2 v00 = im[x0*NXI + y0];
        float2 v10 = im[x1*NXI + y0];
        float2 v01 = im[x0*NXI + y1];
        float2 v11 = im[x1*NXI + y1];
        float w00 = (1.f-dx)*(1.f-dy), w10 = dx*(1.f-dy);
        float w01 = (1.f-dx)*dy,       w11 = dx*dy;
        accr += w00*v00.x + w10*v10.x + w01*v01.x + w11*v11.x;
        acci += w00*v00.y + w10*v10.y + w01*v01.y + w11*v11.y;
    }
    out[pix*2+0] = accr;
    out[pix*2+1] = acci;
}

extern "C" void kernel_launch(void* const* d_in, const int* in_sizes, int n_in,
                              void* d_out, int out_size, void* d_ws, size_t ws_size,
                              hipStream_t stream)
{
    const float* kr   = (const float*)d_in[0];
    const float* ki   = (const float*)d_in[1];
    const float* traj = (const float*)d_in[2];
    const float* csr  = (const float*)d_in[3];
    const float* csi  = (const float*)d_in[4];
    const float* dcf  = (const float*)d_in[5];
    const float* mot  = (const float*)d_in[6];
    float* out = (float*)d_out;

    char* ws = (char*)d_ws;
    float*  recs     = (float*)ws;                       // 41.94 MB
    ws += (size_t)NTI * MI * REC_F * sizeof(float);
    v2f*    rowout   = (v2f*)ws;                         // 104.86 MB
    ws += (size_t)NTI * NCI * GI * NXI * sizeof(float2);
    float2* colimg   = (float2*)ws;                      // 52.43 MB
    ws += (size_t)NTI * NCI * NPIX * sizeof(float2);
    float2* img      = (float2*)ws;                      // 6.55 MB
    ws += (size_t)NTI * NPIX * sizeof(float2);
    int*    counts   = (int*)ws;  ws += (size_t)NBINS * sizeof(int);        // 13.1 MB
    int*    binstart = (int*)ws;  ws += ((size_t)NBINS + 16) * sizeof(int); // 13.1 MB
    int*    sums     = (int*)ws;  ws += 16384;

    hipMemsetAsync(counts, 0, (size_t)NBINS * sizeof(int), stream);
    count_cells  <<<NTI*MI/256, 256, 0, stream>>>(traj, counts);
    scanA        <<<SCAN_BLKS, 1024, 0, stream>>>(counts, binstart, sums);
    scanB        <<<1,         1024, 0, stream>>>(sums, binstart);
    scatter_cells<<<NTI*MI/256, 256, 0, stream>>>(kr, ki, traj, dcf, counts,
                                                  binstart, sums, recs);
    row_fft      <<<NTI*GI,     512, 0, stream>>>(binstart, sums, recs, rowout);
    col_fft      <<<NTI*NCI*40, 512, 0, stream>>>(rowout, (v2f*)colimg);
    combine_kernel<<<dim3(NPIX/256, NTI), 256, 0, stream>>>(colimg, csr, csi, img);
    warp_sum     <<<NPIX/256,   256, 0, stream>>>(img, mot, out);
}

// Round 11
// 288.364 us; speedup vs baseline: 1.6729x; 1.0561x over previous
//
#include <hip/hip_runtime.h>
#include <math.h>

#define NXI 320
#define NCI 8
#define NTI 8
#define MI  65536
#define GI  640
#define G2I (GI*GI)
#define NPIX (NXI*NXI)
#define REC_F 20          // floats per record: {du,dv,0,0, 8x(re,im)}
#define NBINS (NTI*G2I)   // 3,276,800 cells over all frames
#define SCAN_BLKS2 (NBINS/4096)   // 800 (4096 bins per block)

typedef float v2f __attribute__((ext_vector_type(2)));

__device__ inline v2f cmul(v2f a, v2f b) {
    v2f axx = __builtin_shufflevector(a, a, 0, 0);
    v2f ayy = __builtin_shufflevector(a, a, 1, 1);
    v2f byx = __builtin_shufflevector(b, b, 1, 0);
    v2f r = axx * b;
    v2f t = ayy * byx;
    return r + v2f{-t.x, t.y};
}

// lane permutation for butterfly stage H: DPP where the pattern fits a
// 16-row permutation (zero DS traffic), ds_swizzle otherwise.
template<int H>
__device__ inline float sxf(float x) {
    if constexpr (H == 1) {        // quad_perm [1,0,3,2]
        return __int_as_float(__builtin_amdgcn_update_dpp(
            __float_as_int(x), __float_as_int(x), 0xB1, 0xF, 0xF, false));
    } else if constexpr (H == 2) { // quad_perm [2,3,0,1]
        return __int_as_float(__builtin_amdgcn_update_dpp(
            __float_as_int(x), __float_as_int(x), 0x4E, 0xF, 0xF, false));
    } else if constexpr (H == 8) { // row_ror:8 == xor-8 within 16-row
        return __int_as_float(__builtin_amdgcn_update_dpp(
            __float_as_int(x), __float_as_int(x), 0x128, 0xF, 0xF, false));
    } else {
        return __shfl_xor(x, H, 64);
    }
}
template<int H>
__device__ inline v2f sxv(v2f v) { return v2f{sxf<H>(v.x), sxf<H>(v.y)}; }

__device__ inline void cell_of(const float* __restrict__ traj, int m, int f,
                               int& i0s, int& j0s, float& du, float& dv)
{
    float tu = traj[(m*2 + 0)*NTI + f];
    float tv = traj[(m*2 + 1)*NTI + f];
    float u = (tu + 0.5f) * (float)GI;
    float v = (tv + 0.5f) * (float)GI;
    float fu = floorf(u), fv = floorf(v);
    du = u - fu; dv = v - fv;
    i0s = (int)fu + GI/2; if (i0s >= GI) i0s -= GI;   // ifftshift folded in
    j0s = (int)fv + GI/2; if (j0s >= GI) j0s -= GI;
}

// ---------------- cell-level counting sort, all frames ----------------
__global__ __launch_bounds__(256) void count_cells(
    const float* __restrict__ traj, int* __restrict__ counts)
{
    int tid = blockIdx.x * 256 + threadIdx.x;   // f*MI + m
    int f = tid >> 16, m = tid & (MI - 1);
    int i0s, j0s; float du, dv;
    cell_of(traj, m, f, i0s, j0s, du, dv);
    atomicAdd(&counts[f*G2I + i0s*GI + j0s], 1);
}

__device__ inline int wave_incl_scan(int v, int lane) {
    #pragma unroll
    for (int d = 1; d < 64; d <<= 1) {
        int y = __shfl_up(v, d, 64);
        if (lane >= d) v += y;
    }
    return v;
}

// 4096 bins per block, barrier-light: wave shuffle scan + 16-entry cross-wave
__global__ __launch_bounds__(1024) void scanA(const int4* __restrict__ counts4,
                                              int4* __restrict__ binstart4,
                                              int* __restrict__ sums)
{
    __shared__ int wtot[16];
    int tid = threadIdx.x, lane = tid & 63, wv = tid >> 6;
    int i = blockIdx.x * 1024 + tid;
    int4 c = counts4[i];
    int s = c.x + c.y + c.z + c.w;
    int incl = wave_incl_scan(s, lane);
    if (lane == 63) wtot[wv] = incl;
    __syncthreads();
    if (wv == 0 && lane < 16) {
        int t = wtot[lane];
        #pragma unroll
        for (int d = 1; d < 16; d <<= 1) {
            int y = __shfl_up(t, d, 64);
            if (lane >= d) t += y;
        }
        wtot[lane] = t;     // inclusive over waves
    }
    __syncthreads();
    int woff = wv ? wtot[wv - 1] : 0;
    int excl = woff + incl - s;
    int4 b;
    b.x = excl; b.y = excl + c.x; b.z = b.y + c.y; b.w = b.z + c.z;
    binstart4[i] = b;
    if (tid == 1023) sums[blockIdx.x] = woff + incl;   // block total
}

// one block: exclusive scan of the 800 chunk sums + sentinels
__global__ __launch_bounds__(1024) void scanB(int* __restrict__ sums,
                                              int* __restrict__ binstart)
{
    __shared__ int tmp[1024];
    int tid = threadIdx.x;
    int v = (tid < SCAN_BLKS2) ? sums[tid] : 0;
    tmp[tid] = v; __syncthreads();
    for (int d = 1; d < 1024; d <<= 1) {
        int y = (tid >= d) ? tmp[tid - d] : 0;
        __syncthreads();
        tmp[tid] += y;
        __syncthreads();
    }
    int incl = tmp[tid];
    if (tid < SCAN_BLKS2) sums[tid] = incl - v;
    if (tid == SCAN_BLKS2 - 1) {
        sums[SCAN_BLKS2] = incl;        // == grand total: sentinel chunk
        binstart[NBINS] = 0;            // so GS(NBINS) == total
    }
}

// slot via atomicSub on counts — no cursor array
__global__ __launch_bounds__(256) void scatter_cells(
    const float* __restrict__ kr, const float* __restrict__ ki,
    const float* __restrict__ traj, const float* __restrict__ dcf,
    int* __restrict__ counts, const int* __restrict__ binstart,
    const int* __restrict__ sums, float* __restrict__ recs)
{
    int tid = blockIdx.x * 256 + threadIdx.x;   // f*MI + m
    int f = tid >> 16, m = tid & (MI - 1);
    int i0s, j0s; float du, dv;
    cell_of(traj, m, f, i0s, j0s, du, dv);
    float w = dcf[m*NTI + f];
    int bin = f*G2I + i0s*GI + j0s;
    int within = atomicSub(&counts[bin], 1) - 1;
    int slot = binstart[bin] + sums[bin >> 12] + within;
    float4* r = (float4*)(recs + (size_t)slot * REC_F);
    r[0] = make_float4(du, dv, 0.f, 0.f);
    #pragma unroll
    for (int q = 0; q < 4; ++q) {
        int c0 = 2*q;
        r[1+q] = make_float4(kr[c0*MI + m]*w,     ki[c0*MI + m]*w,
                             kr[(c0+1)*MI + m]*w, ki[(c0+1)*MI + m]*w);
    }
}

// ---------------- register-resident 640-pt iFFT (sign +), packed ----------------
__device__ inline void dft5p(v2f x0, v2f x1, v2f x2, v2f x3, v2f x4, v2f* X)
{
    const float c1 = 0.309016994f, c2 = -0.809016994f;
    const float s1 = 0.951056516f, s2 =  0.587785252f;
    v2f S1 = x1 + x4, D1 = x1 - x4;
    v2f S2 = x2 + x3, D2 = x2 - x3;
    X[0] = x0 + S1 + S2;
    v2f A = x0 + c1*S1 + c2*S2;
    v2f T = s1*D1 + s2*D2;
    v2f B = x0 + c2*S1 + c1*S2;
    v2f U = s2*D1 - s1*D2;
    v2f iT = v2f{-T.y, T.x};
    v2f iU = v2f{-U.y, U.x};
    X[1] = A + iT;  X[4] = A - iT;
    X[2] = B + iU;  X[3] = B - iU;
}

// one DIF butterfly stage (compile-time H), r5-verified sign convention
template<int H, int S>
__device__ inline void bf_stage(v2f* a, int lane)
{
    const float PI = 3.14159265358979f;
    bool low = (lane & H) == 0;
    int kp = (lane << S) & 31;
    float sn, cs;
    __sincosf((2.0f * PI / 64.0f) * (float)kp, &sn, &cs);
    v2f w = low ? v2f{1.f, 0.f} : v2f{cs, sn};
    float sg = low ? 1.f : -1.f;
    v2f sgv = v2f{sg, sg};
    #pragma unroll
    for (int n = 0; n < 10; ++n) {
        v2f p = sxv<H>(a[n]);
        v2f t = sgv * a[n] + p;        // low: p+a ; high: p-a
        a[n] = cmul(t, w);
    }
}

__device__ inline void fft640_pruned(v2f* a, int lane, v2f* line, int xorm)
{
    const float PI = 3.14159265358979f;
    bf_stage<32, 0>(a, lane);
    bf_stage<16, 1>(a, lane);
    bf_stage< 8, 2>(a, lane);
    bf_stage< 4, 3>(a, lane);
    bf_stage< 2, 4>(a, lane);
    bf_stage< 1, 5>(a, lane);
    int k1 = __brev(lane) >> 26;
    float th2 = (2.0f * PI / 640.0f) * (float)k1;
    float sn, cs;
    __sincosf(th2, &sn, &cs);
    v2f wb = v2f{cs, sn};
    v2f w = wb;
    #pragma unroll
    for (int n = 1; n < 10; ++n) {
        a[n] = cmul(a[n], w);
        w = cmul(w, wb);
    }
    v2f E[5], O[5];
    dft5p(a[0], a[2], a[4], a[6], a[8], E);
    dft5p(a[1], a[3], a[5], a[7], a[9], O);
    const v2f tk1 = { 0.809016994f, 0.587785252f};
    const v2f tk2 = { 0.309016994f, 0.951056516f};
    const v2f tk3 = {-0.309016994f, 0.951056516f};
    const v2f tk4 = {-0.809016994f, 0.587785252f};
    v2f t1 = cmul(tk1, O[1]);
    v2f t2 = cmul(tk2, O[2]);
    v2f t3 = cmul(tk3, O[3]);
    v2f t4 = cmul(tk4, O[4]);
    bool hi = (k1 >= 32);
    line[(160 + k1) ^ xorm] = E[0] + O[0];          // k2=0
    line[(224 + k1) ^ xorm] = E[1] + t1;            // k2=1
    int yx = hi ? (k1 - 32) : (288 + k1);           // k2=7 : k2=2
    v2f zx = hi ? (E[2] - t2) : (E[2] + t2);
    line[yx ^ xorm] = zx;
    line[(32 + k1) ^ xorm] = E[3] - t3;             // k2=8
    line[(96 + k1) ^ xorm] = E[4] - t4;             // k2=9
}

// ---- fused atomic-free gather + row FFT: block = (frame, grid-row i) ----
__global__ __launch_bounds__(512, 8) void row_fft(
    const int* __restrict__ binstart, const int* __restrict__ sums,
    const float* __restrict__ recs, v2f* __restrict__ rowout)
{
    __shared__ v2f A[NCI][GI];      // 40,960 B exactly -> 4 blocks/CU
    int bid = blockIdx.x;           // f*GI + i
    int i = bid % GI;
    int f = bid / GI;
    int tid = threadIdx.x;
    int im1 = i ? i - 1 : GI - 1;
    const int base0 = f*G2I + i*GI;     // p=0: row i   (1-du)
    const int base1 = f*G2I + im1*GI;   // p=1: row i-1 (du)

    #define GS(b) (binstart[b] + sums[(b) >> 12])

    for (int j = tid; j < GI; j += 512) {
        v2f acc[NCI];
        #pragma unroll
        for (int c = 0; c < NCI; ++c) acc[c] = v2f{0.f, 0.f};
        #pragma unroll
        for (int p = 0; p < 2; ++p) {
            const int base = p ? base1 : base0;
            if (j > 0) {
                int lo = GS(base + j - 1), mid = GS(base + j), hi = GS(base + j + 1);
                for (int s = lo; s < hi; ++s) {
                    const float4* R = (const float4*)(recs + (size_t)s*REC_F);
                    float4 h4 = R[0];
                    float wr = p ? h4.x : (1.f - h4.x);
                    float w  = wr * ((s < mid) ? h4.y : (1.f - h4.y));
                    float4 d0 = R[1], d1 = R[2], d2 = R[3], d3 = R[4];
                    acc[0] += w * v2f{d0.x, d0.y};  acc[1] += w * v2f{d0.z, d0.w};
                    acc[2] += w * v2f{d1.x, d1.y};  acc[3] += w * v2f{d1.z, d1.w};
                    acc[4] += w * v2f{d2.x, d2.y};  acc[5] += w * v2f{d2.z, d2.w};
                    acc[6] += w * v2f{d3.x, d3.y};  acc[7] += w * v2f{d3.z, d3.w};
                }
            } else {
                #pragma unroll
                for (int side = 0; side < 2; ++side) {
                    int b = base + (side ? 0 : (GI - 1));
                    int s0 = GS(b), s1 = GS(b + 1);
                    for (int s = s0; s < s1; ++s) {
                        const float4* R = (const float4*)(recs + (size_t)s*REC_F);
                        float4 h4 = R[0];
                        float wr = p ? h4.x : (1.f - h4.x);
                        float w  = wr * (side ? (1.f - h4.y) : h4.y);
                        float4 d0 = R[1], d1 = R[2], d2 = R[3], d3 = R[4];
                        acc[0] += w * v2f{d0.x, d0.y};  acc[1] += w * v2f{d0.z, d0.w};
                        acc[2] += w * v2f{d1.x, d1.y};  acc[3] += w * v2f{d1.z, d1.w};
                        acc[4] += w * v2f{d2.x, d2.y};  acc[5] += w * v2f{d2.z, d2.w};
                        acc[6] += w * v2f{d3.x, d3.y};  acc[7] += w * v2f{d3.z, d3.w};
                    }
                }
            }
        }
        #pragma unroll
        for (int c = 0; c < NCI; ++c) A[c][j] = acc[c];
    }
    #undef GS
    __syncthreads();

    int wv = tid >> 6, lane = tid & 63;
    v2f a[10];
    #pragma unroll
    for (int n = 0; n < 10; ++n) a[n] = A[wv][10*lane + n];
    fft640_pruned(a, lane, A[wv], 0);
    v2f* dst = rowout + (((size_t)f*NCI + wv)*GI + i)*NXI;
    #pragma unroll
    for (int q = 0; q < 5; ++q) {
        int yc = lane + 64*q;
        dst[yc] = A[wv][yc];
    }
}

// ---- col FFT + crop: block = (frame, coil, y-group of 8) ----
__global__ __launch_bounds__(512, 8) void col_fft(
    const v2f* __restrict__ rowout, v2f* __restrict__ colimg)
{
    __shared__ v2f A[8][GI];
    int bid = blockIdx.x;
    int g = bid % 40;
    int c = (bid / 40) % NCI;
    int f = bid / (40*NCI);
    int y0 = g * 8;
    int tid = threadIdx.x;
    const v2f* src = rowout + ((size_t)f*NCI + c)*GI*NXI + y0;
    for (int idx = tid; idx < 8*GI; idx += 512) {
        int l = idx & 7, k = idx >> 3;
        A[l][k ^ (4*(l & 3))] = src[(size_t)k*NXI + l];
    }
    __syncthreads();
    int wv = tid >> 6, lane = tid & 63;
    int xm = 4 * (wv & 3);
    v2f a[10];
    #pragma unroll
    for (int n = 0; n < 10; ++n) a[n] = A[wv][(10*lane + n) ^ xm];
    fft640_pruned(a, lane, A[wv], xm);
    __syncthreads();
    v2f* dst = colimg + ((size_t)f*NCI + c)*NPIX + y0;
    for (int idx = tid; idx < 8*NXI; idx += 512) {
        int l = idx & 7, xx = idx >> 3;
        dst[(size_t)xx*NXI + l] = A[l][xx ^ (4*(l & 3))];
    }
}

// ------------- deapodize + coil combine -------------
__global__ __launch_bounds__(256) void combine_kernel(
    const float2* __restrict__ colimg, const float* __restrict__ csr,
    const float* __restrict__ csi, float2* __restrict__ img)
{
    int f = blockIdx.y;
    int pix = blockIdx.x * 256 + threadIdx.x;
    int x = pix / NXI, y = pix - x*NXI;
    const float PI = 3.14159265358979f;
    float tx = (x - 160) * (1.0f/GI);
    float ty = (y - 160) * (1.0f/GI);
    float dx = 1.0f, dy = 1.0f;
    if (x != 160) { float s = __sinf(PI*tx) / (PI*tx); dx = s*s; }
    if (y != 160) { float s = __sinf(PI*ty) / (PI*ty); dy = s*s; }
    float scale = 1.0f / ((float)G2I * dx * dy);
    float accr = 0.f, acci = 0.f;
    #pragma unroll
    for (int c = 0; c < NCI; ++c) {
        float2 g = colimg[((size_t)f*NCI + c)*NPIX + pix];
        float cr = csr[c*NPIX + pix];
        float ci = csi[c*NPIX + pix];
        accr += cr*g.x + ci*g.y;
        acci += cr*g.y - ci*g.x;
    }
    img[(size_t)f*NPIX + pix] = make_float2(accr*scale, acci*scale);
}

// ---------------- warp all frames + sum ----------------
__global__ __launch_bounds__(256) void warp_sum(
    const float2* __restrict__ img, const float* __restrict__ motions,
    float* __restrict__ out)
{
    int pix = blockIdx.x * 256 + threadIdx.x;
    int x = pix / NXI, y = pix - x*NXI;
    float accr = 0.f, acci = 0.f;
    #pragma unroll
    for (int f = 0; f < NTI; ++f) {
        float fx = motions[(size_t)(pix*2 + 0)*NTI + f];
        float fy = motions[(size_t)(pix*2 + 1)*NTI + f];
        float xs = fminf(fmaxf((float)x + fx, 0.0f), (float)(NXI-1));
        float ys = fminf(fmaxf((float)y + fy, 0.0f), (float)(NXI-1));
        int x0 = (int)floorf(xs);
        int y0 = (int)floorf(ys);
        int x1 = min(x0+1, NXI-1);
        int y1 = min(y0+1, NXI-1);
        float dx = xs - (float)x0;
        float dy = ys - (float)y0;
        const float2* im = img + (size_t)f*NPIX;
        float2 v00 = im[x0*NXI + y0];
        float2 v10 = im[x1*NXI + y0];
        float2 v01 = im[x0*NXI + y1];
        float2 v11 = im[x1*NXI + y1];
        float w00 = (1.f-dx)*(1.f-dy), w10 = dx*(1.f-dy);
        float w01 = (1.f-dx)*dy,       w11 = dx*dy;
        accr += w00*v00.x + w10*v10.x + w01*v01.x + w11*v11.x;
        acci += w00*v00.y + w10*v10.y + w01*v01.y + w11*v11.y;
    }
    out[pix*2+0] = accr;
    out[pix*2+1] = acci;
}

extern "C" void kernel_launch(void* const* d_in, const int* in_sizes, int n_in,
                              void* d_out, int out_size, void* d_ws, size_t ws_size,
                              hipStream_t stream)
{
    const float* kr   = (const float*)d_in[0];
    const float* ki   = (const float*)d_in[1];
    const float* traj = (const float*)d_in[2];
    const float* csr  = (const float*)d_in[3];
    const float* csi  = (const float*)d_in[4];
    const float* dcf  = (const float*)d_in[5];
    const float* mot  = (const float*)d_in[6];
    float* out = (float*)d_out;

    char* ws = (char*)d_ws;
    float*  recs     = (float*)ws;                       // 41.94 MB
    ws += (size_t)NTI * MI * REC_F * sizeof(float);
    v2f*    rowout   = (v2f*)ws;                         // 104.86 MB
    ws += (size_t)NTI * NCI * GI * NXI * sizeof(float2);
    float2* colimg   = (float2*)ws;                      // 52.43 MB
    ws += (size_t)NTI * NCI * NPIX * sizeof(float2);
    float2* img      = (float2*)ws;                      // 6.55 MB
    ws += (size_t)NTI * NPIX * sizeof(float2);
    int*    counts   = (int*)ws;  ws += (size_t)NBINS * sizeof(int);        // 13.1 MB
    int*    binstart = (int*)ws;  ws += ((size_t)NBINS + 16) * sizeof(int); // 13.1 MB
    int*    sums     = (int*)ws;  ws += 16384;

    hipMemsetAsync(counts, 0, (size_t)NBINS * sizeof(int), stream);
    count_cells  <<<NTI*MI/256, 256, 0, stream>>>(traj, counts);
    scanA        <<<SCAN_BLKS2, 1024, 0, stream>>>((const int4*)counts,
                                                   (int4*)binstart, sums);
    scanB        <<<1,          1024, 0, stream>>>(sums, binstart);
    scatter_cells<<<NTI*MI/256, 256, 0, stream>>>(kr, ki, traj, dcf, counts,
                                                  binstart, sums, recs);
    row_fft      <<<NTI*GI,     512, 0, stream>>>(binstart, sums, recs, rowout);
    col_fft      <<<NTI*NCI*40, 512, 0, stream>>>(rowout, (v2f*)colimg);
    combine_kernel<<<dim3(NPIX/256, NTI), 256, 0, stream>>>(colimg, csr, csi, img);
    warp_sum     <<<NPIX/256,   256, 0, stream>>>(img, mot, out);
}